// Round 1
// baseline (491.105 us; speedup 1.0000x reference)
//
#include <hip/hip_runtime.h>
#include <stdint.h>

typedef __attribute__((ext_vector_type(4))) float  floatx4;   // MFMA C/D frag
typedef __attribute__((ext_vector_type(8))) short  shortx8;   // MFMA A/B frag (8 bf16)
typedef __attribute__((ext_vector_type(4))) unsigned short ushortx4;

#define TILE    128
#define BK      64
#define LDA     72      // padded LDS row length in bf16 elems (144 B = 9*16B)
#define THREADS 256

__device__ __forceinline__ unsigned short f2bf(float f) {
    unsigned u = __builtin_bit_cast(unsigned, f);
    u += 0x7FFFu + ((u >> 16) & 1u);   // round-to-nearest-even
    return (unsigned short)(u >> 16);
}

__global__ __launch_bounds__(THREADS, 2)
void wql_kernel(const float* __restrict__ x,
                const int*   __restrict__ pw,
                const float* __restrict__ scale,
                const int*   __restrict__ pzp,
                const float* __restrict__ bias,
                float*       __restrict__ out,
                int M, int O, int I, int ng)
{
    __shared__ unsigned short As[TILE * LDA];
    __shared__ unsigned short Bs[TILE * LDA];

    const int tid    = threadIdx.x;
    const int nblk_n = O / TILE;                 // 32
    const int mt     = blockIdx.x / nblk_n;      // mt-major: x-stripe reuse clusters in time
    const int nt     = blockIdx.x % nblk_n;

    const int w    = tid >> 6;
    const int lane = tid & 63;
    const int wm   = w >> 1, wn = w & 1;         // 2x2 wave grid, 64x64 per wave
    const int l15  = lane & 15, l4 = lane >> 4;

    const int pw_rowlen = I / 8;                 // int32 words per W row
    const int zp_rowlen = (ng + 7) / 8;
    const int GS        = I / ng;                // 128

    floatx4 acc[4][4];
    #pragma unroll
    for (int i = 0; i < 4; i++)
        #pragma unroll
        for (int j = 0; j < 4; j++)
            acc[i][j] = (floatx4){0.f, 0.f, 0.f, 0.f};

    const int nk = I / BK;                       // 64
    for (int kt = 0; kt < nk; kt++) {
        __syncthreads();

        // ---- stage A: x[mt*128 .. +128][kt*64 .. +64] fp32 -> bf16 LDS ----
        #pragma unroll
        for (int it = 0; it < 8; it++) {
            int f   = tid + it * THREADS;        // 0..2047 over 128x16 float4 segs
            int row = f >> 4, seg = f & 15;
            const float4 v = *(const float4*)(x + (size_t)(mt * TILE + row) * I + kt * BK + seg * 4);
            ushortx4 b;
            b.x = f2bf(v.x); b.y = f2bf(v.y); b.z = f2bf(v.z); b.w = f2bf(v.w);
            *(ushortx4*)(&As[row * LDA + seg * 4]) = b;   // 8B store, contiguous across threads
        }

        // ---- stage B: dequant W[nt*128 .. +128][kt*64 .. +64] -> bf16 LDS ----
        const int g = (kt * BK) / GS;            // one quant group per K-tile (BK=64 < GS=128)
        #pragma unroll
        for (int it = 0; it < 4; it++) {
            int e   = tid + it * THREADS;        // 0..1023 over 128x8 int32 words
            int row = e >> 3, c = e & 7;
            int o   = nt * TILE + row;
            int wq  = pw[(size_t)o * pw_rowlen + kt * (BK / 8) + c];
            float s = scale[o * ng + g];
            int zpw = pzp[o * zp_rowlen + (g >> 3)];
            int zp  = (zpw >> ((g & 7) * 4)) & 15;
            shortx8 b;
            #pragma unroll
            for (int j = 0; j < 8; j++) {
                int nib = (wq >> (4 * j)) & 15;
                b[j] = (short)f2bf((float)(nib - zp) * s);
            }
            *(shortx8*)(&Bs[row * LDA + c * 8]) = b;      // 16B store, contiguous across threads
        }

        __syncthreads();

        // ---- MFMA inner loop: 2 k-steps of 32 each ----
        #pragma unroll
        for (int ks = 0; ks < 2; ks++) {
            shortx8 af[4], bf[4];
            #pragma unroll
            for (int i = 0; i < 4; i++)
                af[i] = *(const shortx8*)(&As[(wm * 64 + i * 16 + l15) * LDA + ks * 32 + l4 * 8]);
            #pragma unroll
            for (int j = 0; j < 4; j++)
                bf[j] = *(const shortx8*)(&Bs[(wn * 64 + j * 16 + l15) * LDA + ks * 32 + l4 * 8]);
            #pragma unroll
            for (int i = 0; i < 4; i++)
                #pragma unroll
                for (int j = 0; j < 4; j++)
                    acc[i][j] = __builtin_amdgcn_mfma_f32_16x16x32_bf16(af[i], bf[j], acc[i][j], 0, 0, 0);
        }
    }

    // ---- epilogue: C = acc + bias ----
    #pragma unroll
    for (int j = 0; j < 4; j++) {
        int col  = nt * TILE + wn * 64 + j * 16 + l15;
        float bv = bias[col];
        #pragma unroll
        for (int i = 0; i < 4; i++) {
            int rowb = mt * TILE + wm * 64 + i * 16 + l4 * 4;
            #pragma unroll
            for (int r = 0; r < 4; r++)
                out[(size_t)(rowb + r) * O + col] = acc[i][j][r] + bv;
        }
    }
}

extern "C" void kernel_launch(void* const* d_in, const int* in_sizes, int n_in,
                              void* d_out, int out_size, void* d_ws, size_t ws_size,
                              hipStream_t stream) {
    const float* x     = (const float*)d_in[0];
    const int*   pw    = (const int*)d_in[1];
    const float* scale = (const float*)d_in[2];
    const int*   pzp   = (const int*)d_in[3];
    const float* bias  = (const float*)d_in[4];
    float*       out   = (float*)d_out;

    const int O  = in_sizes[4];                   // 4096
    const int ng = in_sizes[2] / O;               // 32
    const int I  = (in_sizes[1] / O) * 8;         // 4096
    const int M  = in_sizes[0] / I;               // 4096

    dim3 grid((M / TILE) * (O / TILE));           // 1024 blocks, mt-major
    wql_kernel<<<grid, THREADS, 0, stream>>>(x, pw, scale, pzp, bias, out, M, O, I, ng);
}

// Round 2
// 287.908 us; speedup vs baseline: 1.7058x; 1.7058x over previous
//
#include <hip/hip_runtime.h>
#include <stdint.h>

typedef __attribute__((ext_vector_type(4))) float  floatx4;   // MFMA C/D frag
typedef __attribute__((ext_vector_type(8))) short  shortx8;   // MFMA A/B frag (8 bf16)
typedef __attribute__((ext_vector_type(4))) unsigned short ushortx4;

typedef unsigned int   u32;
typedef unsigned short u16;

#define TILE    128
#define BK      64
#define THREADS 256
#define CHUNK   (TILE * BK)    // 8192 bf16 elems = 16 KB per (tile, ktile) chunk

// ---- round-to-nearest-ish bf16 pack: +0x8000 then take high halves via v_perm ----
__device__ __forceinline__ u32 pack2bf(float f0, float f1) {
    u32 u0 = __builtin_bit_cast(u32, f0) + 0x8000u;
    u32 u1 = __builtin_bit_cast(u32, f1) + 0x8000u;
    return __builtin_amdgcn_perm(u1, u0, 0x07060302u);  // {u1.hi16, u0.hi16}
}

__device__ __forceinline__ unsigned short f2bf(float f) {
    u32 u = __builtin_bit_cast(u32, f);
    u += 0x7FFFu + ((u >> 16) & 1u);
    return (unsigned short)(u >> 16);
}

// ======================= prep kernel 1: x fp32 -> bf16, pre-tiled =======================
// At chunk layout: [mt][kt] -> 128x64 bf16 row-major (exact LDS image for the GEMM).
__global__ __launch_bounds__(THREADS)
void convert_x(const float* __restrict__ x, u16* __restrict__ At, int I, int KT) {
    const int row  = blockIdx.x;
    const int cseg = blockIdx.y * THREADS + threadIdx.x;   // 8-float segment within row
    const int col  = cseg * 8;
    const int mt = row >> 7, r = row & 127;
    const int kt = col >> 6, cs = (col >> 3) & 7;
    const float4 v0 = *(const float4*)(x + (size_t)row * I + col);
    const float4 v1 = *(const float4*)(x + (size_t)row * I + col + 4);
    u32 p[4];
    p[0] = pack2bf(v0.x, v0.y);
    p[1] = pack2bf(v0.z, v0.w);
    p[2] = pack2bf(v1.x, v1.y);
    p[3] = pack2bf(v1.z, v1.w);
    *(uint4*)(At + (size_t)(mt * KT + kt) * CHUNK + r * BK + cs * 8) = *(uint4*)p;
}

// ======================= prep kernel 2: W int4 -> bf16 dequant, pre-tiled =======================
// magic: bitcast(0x43000000 | nib<<16) == 128+nib; (nib-zp)*s == fma(magic, s, -s*(zp+128))
__global__ __launch_bounds__(THREADS)
void dequant_w(const int* __restrict__ pw, const float* __restrict__ scale,
               const int* __restrict__ pzp, u16* __restrict__ Bt,
               int I, int ng, int KT) {
    const int o    = blockIdx.x;
    const int wcol = blockIdx.y * THREADS + threadIdx.x;   // int32-word col within W row
    const int g  = wcol >> 4;                              // 16 words per 128-k group
    const int kt = wcol >> 3, cs = wcol & 7;
    const int nt = o >> 7, r = o & 127;
    const u32 wq = (u32)pw[(size_t)o * (I >> 3) + wcol];
    const float s = scale[o * ng + g];
    const int zpw = pzp[o * ((ng + 7) >> 3) + (g >> 3)];
    const int zp  = (zpw >> ((g & 7) * 4)) & 15;
    const float nzc = -s * (float)(zp + 128);
    float v[8];
    #pragma unroll
    for (int j = 0; j < 8; j++) {
        u32 t;
        if (j < 4)       t = (wq << (16 - 4 * j)) & 0x000F0000u;
        else if (j == 4) t = wq & 0x000F0000u;
        else             t = (wq >> (4 * j - 16)) & 0x000F0000u;
        float f = __builtin_bit_cast(float, t | 0x43000000u);  // 128 + nib, exact
        v[j] = __builtin_fmaf(f, s, nzc);
    }
    u32 p[4];
    p[0] = pack2bf(v[0], v[1]);
    p[1] = pack2bf(v[2], v[3]);
    p[2] = pack2bf(v[4], v[5]);
    p[3] = pack2bf(v[6], v[7]);
    *(uint4*)(Bt + (size_t)(nt * KT + kt) * CHUNK + r * BK + cs * 8) = *(uint4*)p;
}

// ======================= main GEMM: m97 structure, global_load_lds staging =======================
__global__ __launch_bounds__(THREADS, 2)
void gemm_bf16(const u16* __restrict__ At, const u16* __restrict__ Bt,
               const float* __restrict__ bias, float* __restrict__ out,
               int O, int KT) {
    __shared__ u16 As[CHUNK];
    __shared__ u16 Bs[CHUNK];

    const int tid = threadIdx.x;
    const int nblk_n = O / TILE;
    const int mt = blockIdx.x / nblk_n;      // mt-major: A-chunk reuse clusters in time
    const int nt = blockIdx.x % nblk_n;
    const int w = tid >> 6, lane = tid & 63;
    const int wm = w >> 1, wn = w & 1;       // 2x2 wave grid, 64x64 per wave
    const int l15 = lane & 15, l4 = lane >> 4;

    floatx4 acc[4][4];
    #pragma unroll
    for (int i = 0; i < 4; i++)
        #pragma unroll
        for (int j = 0; j < 4; j++)
            acc[i][j] = (floatx4){0.f, 0.f, 0.f, 0.f};

    for (int kt = 0; kt < KT; kt++) {
        const u16* ga = At + (size_t)(mt * KT + kt) * CHUNK;
        const u16* gb = Bt + (size_t)(nt * KT + kt) * CHUNK;
        __syncthreads();                      // previous tile fully consumed
        #pragma unroll
        for (int it = 0; it < 4; it++) {
            const int off = (it * THREADS + tid) * 8;   // 16 B per thread per issue
            __builtin_amdgcn_global_load_lds((const __attribute__((address_space(1))) u32*)(ga + off),
                                             (__attribute__((address_space(3))) u32*)(As + off),
                                             16, 0, 0);
            __builtin_amdgcn_global_load_lds((const __attribute__((address_space(1))) u32*)(gb + off),
                                             (__attribute__((address_space(3))) u32*)(Bs + off),
                                             16, 0, 0);
        }
        __syncthreads();                      // vmcnt(0) drain: tiles visible

        #pragma unroll
        for (int ks = 0; ks < 2; ks++) {
            shortx8 af[4], bf[4];
            #pragma unroll
            for (int i = 0; i < 4; i++)
                af[i] = *(const shortx8*)(&As[(wm * 64 + i * 16 + l15) * BK + ks * 32 + l4 * 8]);
            #pragma unroll
            for (int j = 0; j < 4; j++)
                bf[j] = *(const shortx8*)(&Bs[(wn * 64 + j * 16 + l15) * BK + ks * 32 + l4 * 8]);
            #pragma unroll
            for (int i = 0; i < 4; i++)
                #pragma unroll
                for (int j = 0; j < 4; j++)
                    acc[i][j] = __builtin_amdgcn_mfma_f32_16x16x32_bf16(af[i], bf[j], acc[i][j], 0, 0, 0);
        }
    }

    #pragma unroll
    for (int j = 0; j < 4; j++) {
        int col  = nt * TILE + wn * 64 + j * 16 + l15;
        float bv = bias[col];
        #pragma unroll
        for (int i = 0; i < 4; i++) {
            int rowb = (blockIdx.x / nblk_n) * TILE + wm * 64 + i * 16 + l4 * 4;
            #pragma unroll
            for (int r = 0; r < 4; r++)
                out[(size_t)(rowb + r) * O + col] = acc[i][j][r] + bv;
        }
    }
}

// ======================= fallback (round-1 fused kernel) if ws too small =======================
#define LDA 72
__global__ __launch_bounds__(THREADS, 2)
void wql_fused(const float* __restrict__ x, const int* __restrict__ pw,
               const float* __restrict__ scale, const int* __restrict__ pzp,
               const float* __restrict__ bias, float* __restrict__ out,
               int M, int O, int I, int ng)
{
    __shared__ unsigned short As[TILE * LDA];
    __shared__ unsigned short Bs[TILE * LDA];
    const int tid = threadIdx.x;
    const int nblk_n = O / TILE;
    const int mt = blockIdx.x / nblk_n, nt = blockIdx.x % nblk_n;
    const int w = tid >> 6, lane = tid & 63;
    const int wm = w >> 1, wn = w & 1;
    const int l15 = lane & 15, l4 = lane >> 4;
    const int pw_rowlen = I / 8, zp_rowlen = (ng + 7) / 8, GS = I / ng;

    floatx4 acc[4][4];
    #pragma unroll
    for (int i = 0; i < 4; i++)
        #pragma unroll
        for (int j = 0; j < 4; j++) acc[i][j] = (floatx4){0.f, 0.f, 0.f, 0.f};

    const int nk = I / BK;
    for (int kt = 0; kt < nk; kt++) {
        __syncthreads();
        #pragma unroll
        for (int it = 0; it < 8; it++) {
            int f = tid + it * THREADS;
            int row = f >> 4, seg = f & 15;
            const float4 v = *(const float4*)(x + (size_t)(mt * TILE + row) * I + kt * BK + seg * 4);
            ushortx4 b;
            b.x = f2bf(v.x); b.y = f2bf(v.y); b.z = f2bf(v.z); b.w = f2bf(v.w);
            *(ushortx4*)(&As[row * LDA + seg * 4]) = b;
        }
        const int g = (kt * BK) / GS;
        #pragma unroll
        for (int it = 0; it < 4; it++) {
            int e = tid + it * THREADS;
            int row = e >> 3, c = e & 7;
            int o = nt * TILE + row;
            int wq = pw[(size_t)o * pw_rowlen + kt * (BK / 8) + c];
            float s = scale[o * ng + g];
            int zpw = pzp[o * zp_rowlen + (g >> 3)];
            int zp = (zpw >> ((g & 7) * 4)) & 15;
            shortx8 b;
            #pragma unroll
            for (int j = 0; j < 8; j++) {
                int nib = (wq >> (4 * j)) & 15;
                b[j] = (short)f2bf((float)(nib - zp) * s);
            }
            *(shortx8*)(&Bs[row * LDA + c * 8]) = b;
        }
        __syncthreads();
        #pragma unroll
        for (int ks = 0; ks < 2; ks++) {
            shortx8 af[4], bf[4];
            #pragma unroll
            for (int i = 0; i < 4; i++)
                af[i] = *(const shortx8*)(&As[(wm * 64 + i * 16 + l15) * LDA + ks * 32 + l4 * 8]);
            #pragma unroll
            for (int j = 0; j < 4; j++)
                bf[j] = *(const shortx8*)(&Bs[(wn * 64 + j * 16 + l15) * LDA + ks * 32 + l4 * 8]);
            #pragma unroll
            for (int i = 0; i < 4; i++)
                #pragma unroll
                for (int j = 0; j < 4; j++)
                    acc[i][j] = __builtin_amdgcn_mfma_f32_16x16x32_bf16(af[i], bf[j], acc[i][j], 0, 0, 0);
        }
    }
    #pragma unroll
    for (int j = 0; j < 4; j++) {
        int col = nt * TILE + wn * 64 + j * 16 + l15;
        float bv = bias[col];
        #pragma unroll
        for (int i = 0; i < 4; i++) {
            int rowb = mt * TILE + wm * 64 + i * 16 + l4 * 4;
            #pragma unroll
            for (int r = 0; r < 4; r++)
                out[(size_t)(rowb + r) * O + col] = acc[i][j][r] + bv;
        }
    }
}

extern "C" void kernel_launch(void* const* d_in, const int* in_sizes, int n_in,
                              void* d_out, int out_size, void* d_ws, size_t ws_size,
                              hipStream_t stream) {
    const float* x     = (const float*)d_in[0];
    const int*   pw    = (const int*)d_in[1];
    const float* scale = (const float*)d_in[2];
    const int*   pzp   = (const int*)d_in[3];
    const float* bias  = (const float*)d_in[4];
    float*       out   = (float*)d_out;

    const int O  = in_sizes[4];                   // 4096
    const int ng = in_sizes[2] / O;               // 32
    const int I  = (in_sizes[1] / O) * 8;         // 4096
    const int M  = in_sizes[0] / I;               // 4096
    const int KT = I / BK;                        // 64

    const size_t need = ((size_t)M * I + (size_t)O * I) * sizeof(u16);  // 64 MB
    if (ws_size >= need) {
        u16* At = (u16*)d_ws;
        u16* Bt = At + (size_t)M * I;
        convert_x<<<dim3(M, I / (8 * THREADS)), THREADS, 0, stream>>>(x, At, I, KT);
        dequant_w<<<dim3(O, I / (8 * THREADS)), THREADS, 0, stream>>>(pw, scale, pzp, Bt, I, ng, KT);
        gemm_bf16<<<dim3((M / TILE) * (O / TILE)), THREADS, 0, stream>>>(At, Bt, bias, out, O, KT);
    } else {
        wql_fused<<<dim3((M / TILE) * (O / TILE)), THREADS, 0, stream>>>(x, pw, scale, pzp, bias, out, M, O, I, ng);
    }
}

// Round 3
// 257.603 us; speedup vs baseline: 1.9064x; 1.1176x over previous
//
#include <hip/hip_runtime.h>
#include <stdint.h>

typedef __attribute__((ext_vector_type(4))) float  floatx4;   // MFMA C/D frag
typedef __attribute__((ext_vector_type(8))) short  shortx8;   // MFMA A/B frag (8 bf16)
typedef __attribute__((ext_vector_type(4))) unsigned short ushortx4;

typedef unsigned int   u32;
typedef unsigned short u16;

#define TILE    128
#define BK      64
#define THREADS 256
#define CHUNK   (TILE * BK)    // 8192 bf16 elems = 16 KB per (tile, ktile) chunk

// ---- bf16 pack: +0x8000 round, take high halves via v_perm ----
__device__ __forceinline__ u32 pack2bf(float f0, float f1) {
    u32 u0 = __builtin_bit_cast(u32, f0) + 0x8000u;
    u32 u1 = __builtin_bit_cast(u32, f1) + 0x8000u;
    return __builtin_amdgcn_perm(u1, u0, 0x07060302u);  // {u1.hi16, u0.hi16}
}

__device__ __forceinline__ unsigned short f2bf(float f) {
    u32 u = __builtin_bit_cast(u32, f);
    u += 0x7FFFu + ((u >> 16) & 1u);
    return (unsigned short)(u >> 16);
}

// ============ fused prep: x fp32->bf16 AND W int4->bf16, pre-tiled + XOR-swizzled ============
// Tile image layout: chunk (16 B = 8 bf16) of logical column-chunk c, row r stored at
// position r*64 + (c ^ (r&7))*8. GEMM stages it linearly via global_load_lds and
// un-swizzles in the fragment-read address -> conflict-free b128 reads.
__global__ __launch_bounds__(THREADS)
void prep_kernel(const float* __restrict__ x, const int* __restrict__ pw,
                 const float* __restrict__ scale, const int* __restrict__ pzp,
                 u16* __restrict__ At, u16* __restrict__ Bt,
                 int M, int O, int I, int ng, int KT) {
    const int bid = blockIdx.x;
    const int t   = threadIdx.x;
    if (bid < M * 2) {
        // ---- convert x: one block = half an x row (2048 floats) ----
        const int row  = bid >> 1;
        const int cseg = (bid & 1) * THREADS + t;     // 8-float segment 0..511
        const int kt = cseg >> 3, cp = cseg & 7;      // output chunk position cp
        const int r = row & (TILE - 1), mt = row >> 7;
        const int c = cp ^ (r & 7);                   // logical chunk to fetch
        const float4 v0 = *(const float4*)(x + (size_t)row * I + kt * BK + c * 8);
        const float4 v1 = *(const float4*)(x + (size_t)row * I + kt * BK + c * 8 + 4);
        u32 p[4];
        p[0] = pack2bf(v0.x, v0.y);
        p[1] = pack2bf(v0.z, v0.w);
        p[2] = pack2bf(v1.x, v1.y);
        p[3] = pack2bf(v1.z, v1.w);
        *(uint4*)(At + (size_t)(mt * KT + kt) * CHUNK + r * BK + cp * 8) = *(uint4*)p;
    } else {
        // ---- dequant W: one block = half a W row (256 int32 words) ----
        const int bid2 = bid - M * 2;
        const int o    = bid2 >> 1;
        const int wpos = (bid2 & 1) * THREADS + t;    // word position 0..511
        const int kt = wpos >> 3, cp = wpos & 7;
        const int r = o & (TILE - 1), nt = o >> 7;
        const int c = cp ^ (r & 7);
        const u32 wq = (u32)pw[(size_t)o * (I >> 3) + kt * 8 + c];
        const int g  = (kt * BK) / (I / ng);          // quant group (BK=64, GS=128 -> kt>>1)
        const float s = scale[o * ng + g];
        const int zpw = pzp[o * ((ng + 7) >> 3) + (g >> 3)];
        const int zp  = (zpw >> ((g & 7) * 4)) & 15;
        const float nzc = -s * (float)(zp + 128);
        float v[8];
        #pragma unroll
        for (int j = 0; j < 8; j++) {
            u32 tt;
            if (j < 4)       tt = (wq << (16 - 4 * j)) & 0x000F0000u;
            else if (j == 4) tt = wq & 0x000F0000u;
            else             tt = (wq >> (4 * j - 16)) & 0x000F0000u;
            float f = __builtin_bit_cast(float, tt | 0x43000000u);  // 128 + nib, exact
            v[j] = __builtin_fmaf(f, s, nzc);
        }
        u32 p[4];
        p[0] = pack2bf(v[0], v[1]);
        p[1] = pack2bf(v[2], v[3]);
        p[2] = pack2bf(v[4], v[5]);
        p[3] = pack2bf(v[6], v[7]);
        *(uint4*)(Bt + (size_t)(nt * KT + kt) * CHUNK + r * BK + cp * 8) = *(uint4*)p;
    }
}

// ======================= main GEMM: m97 structure + swizzled LDS image =======================
__global__ __launch_bounds__(THREADS, 2)
void gemm_bf16(const u16* __restrict__ At, const u16* __restrict__ Bt,
               const float* __restrict__ bias, float* __restrict__ out,
               int O, int KT) {
    __shared__ u16 As[CHUNK];
    __shared__ u16 Bs[CHUNK];

    const int tid = threadIdx.x;
    const int nblk_n = O / TILE;
    const int mt = blockIdx.x / nblk_n;      // mt-major: A-chunk reuse clusters in time
    const int nt = blockIdx.x % nblk_n;
    const int w = tid >> 6, lane = tid & 63;
    const int wm = w >> 1, wn = w & 1;       // 2x2 wave grid, 64x64 per wave
    const int l15 = lane & 15, l4 = lane >> 4;
    const int sw  = l15 & 7;                 // row-dependent XOR for swizzled image

    floatx4 acc[4][4];
    #pragma unroll
    for (int i = 0; i < 4; i++)
        #pragma unroll
        for (int j = 0; j < 4; j++)
            acc[i][j] = (floatx4){0.f, 0.f, 0.f, 0.f};

    for (int kt = 0; kt < KT; kt++) {
        const u16* ga = At + (size_t)(mt * KT + kt) * CHUNK;
        const u16* gb = Bt + (size_t)(nt * KT + kt) * CHUNK;
        __syncthreads();                      // previous tile fully consumed
        #pragma unroll
        for (int it = 0; it < 4; it++) {
            const int off = (it * THREADS + tid) * 8;   // 16 B per thread per issue
            __builtin_amdgcn_global_load_lds((const __attribute__((address_space(1))) u32*)(ga + off),
                                             (__attribute__((address_space(3))) u32*)(As + off),
                                             16, 0, 0);
            __builtin_amdgcn_global_load_lds((const __attribute__((address_space(1))) u32*)(gb + off),
                                             (__attribute__((address_space(3))) u32*)(Bs + off),
                                             16, 0, 0);
        }
        __syncthreads();                      // vmcnt(0) drain: tiles visible

        #pragma unroll
        for (int ks = 0; ks < 2; ks++) {
            shortx8 af[4], bf[4];
            #pragma unroll
            for (int i = 0; i < 4; i++)
                af[i] = *(const shortx8*)(&As[(wm * 64 + i * 16 + l15) * BK + ((ks * 4 + l4) ^ sw) * 8]);
            #pragma unroll
            for (int j = 0; j < 4; j++)
                bf[j] = *(const shortx8*)(&Bs[(wn * 64 + j * 16 + l15) * BK + ((ks * 4 + l4) ^ sw) * 8]);
            #pragma unroll
            for (int i = 0; i < 4; i++)
                #pragma unroll
                for (int j = 0; j < 4; j++)
                    acc[i][j] = __builtin_amdgcn_mfma_f32_16x16x32_bf16(af[i], bf[j], acc[i][j], 0, 0, 0);
        }
    }

    #pragma unroll
    for (int j = 0; j < 4; j++) {
        int col  = nt * TILE + wn * 64 + j * 16 + l15;
        float bv = bias[col];
        #pragma unroll
        for (int i = 0; i < 4; i++) {
            int rowb = mt * TILE + wm * 64 + i * 16 + l4 * 4;
            #pragma unroll
            for (int r = 0; r < 4; r++)
                out[(size_t)(rowb + r) * O + col] = acc[i][j][r] + bv;
        }
    }
}

// ======================= fallback (round-1 fused kernel) if ws too small =======================
#define LDA 72
__global__ __launch_bounds__(THREADS, 2)
void wql_fused(const float* __restrict__ x, const int* __restrict__ pw,
               const float* __restrict__ scale, const int* __restrict__ pzp,
               const float* __restrict__ bias, float* __restrict__ out,
               int M, int O, int I, int ng)
{
    __shared__ unsigned short As[TILE * LDA];
    __shared__ unsigned short Bs[TILE * LDA];
    const int tid = threadIdx.x;
    const int nblk_n = O / TILE;
    const int mt = blockIdx.x / nblk_n, nt = blockIdx.x % nblk_n;
    const int w = tid >> 6, lane = tid & 63;
    const int wm = w >> 1, wn = w & 1;
    const int l15 = lane & 15, l4 = lane >> 4;
    const int pw_rowlen = I / 8, zp_rowlen = (ng + 7) / 8, GS = I / ng;

    floatx4 acc[4][4];
    #pragma unroll
    for (int i = 0; i < 4; i++)
        #pragma unroll
        for (int j = 0; j < 4; j++) acc[i][j] = (floatx4){0.f, 0.f, 0.f, 0.f};

    const int nk = I / BK;
    for (int kt = 0; kt < nk; kt++) {
        __syncthreads();
        #pragma unroll
        for (int it = 0; it < 8; it++) {
            int f = tid + it * THREADS;
            int row = f >> 4, seg = f & 15;
            const float4 v = *(const float4*)(x + (size_t)(mt * TILE + row) * I + kt * BK + seg * 4);
            ushortx4 b;
            b.x = f2bf(v.x); b.y = f2bf(v.y); b.z = f2bf(v.z); b.w = f2bf(v.w);
            *(ushortx4*)(&As[row * LDA + seg * 4]) = b;
        }
        const int g = (kt * BK) / GS;
        #pragma unroll
        for (int it = 0; it < 4; it++) {
            int e = tid + it * THREADS;
            int row = e >> 3, c = e & 7;
            int o = nt * TILE + row;
            int wq = pw[(size_t)o * pw_rowlen + kt * (BK / 8) + c];
            float s = scale[o * ng + g];
            int zpw = pzp[o * zp_rowlen + (g >> 3)];
            int zp = (zpw >> ((g & 7) * 4)) & 15;
            shortx8 b;
            #pragma unroll
            for (int j = 0; j < 8; j++) {
                int nib = (wq >> (4 * j)) & 15;
                b[j] = (short)f2bf((float)(nib - zp) * s);
            }
            *(shortx8*)(&Bs[row * LDA + c * 8]) = b;
        }
        __syncthreads();
        #pragma unroll
        for (int ks = 0; ks < 2; ks++) {
            shortx8 af[4], bf[4];
            #pragma unroll
            for (int i = 0; i < 4; i++)
                af[i] = *(const shortx8*)(&As[(wm * 64 + i * 16 + l15) * LDA + ks * 32 + l4 * 8]);
            #pragma unroll
            for (int j = 0; j < 4; j++)
                bf[j] = *(const shortx8*)(&Bs[(wn * 64 + j * 16 + l15) * LDA + ks * 32 + l4 * 8]);
            #pragma unroll
            for (int i = 0; i < 4; i++)
                #pragma unroll
                for (int j = 0; j < 4; j++)
                    acc[i][j] = __builtin_amdgcn_mfma_f32_16x16x32_bf16(af[i], bf[j], acc[i][j], 0, 0, 0);
        }
    }
    #pragma unroll
    for (int j = 0; j < 4; j++) {
        int col = nt * TILE + wn * 64 + j * 16 + l15;
        float bv = bias[col];
        #pragma unroll
        for (int i = 0; i < 4; i++) {
            int rowb = mt * TILE + wm * 64 + i * 16 + l4 * 4;
            #pragma unroll
            for (int r = 0; r < 4; r++)
                out[(size_t)(rowb + r) * O + col] = acc[i][j][r] + bv;
        }
    }
}

extern "C" void kernel_launch(void* const* d_in, const int* in_sizes, int n_in,
                              void* d_out, int out_size, void* d_ws, size_t ws_size,
                              hipStream_t stream) {
    const float* x     = (const float*)d_in[0];
    const int*   pw    = (const int*)d_in[1];
    const float* scale = (const float*)d_in[2];
    const int*   pzp   = (const int*)d_in[3];
    const float* bias  = (const float*)d_in[4];
    float*       out   = (float*)d_out;

    const int O  = in_sizes[4];                   // 4096
    const int ng = in_sizes[2] / O;               // 32
    const int I  = (in_sizes[1] / O) * 8;         // 4096
    const int M  = in_sizes[0] / I;               // 4096
    const int KT = I / BK;                        // 64

    const size_t need = ((size_t)M * I + (size_t)O * I) * sizeof(u16);  // 64 MB
    if (ws_size >= need) {
        u16* At = (u16*)d_ws;
        u16* Bt = At + (size_t)M * I;
        prep_kernel<<<dim3(M * 2 + O * 2), THREADS, 0, stream>>>(x, pw, scale, pzp, At, Bt, M, O, I, ng, KT);
        gemm_bf16<<<dim3((M / TILE) * (O / TILE)), THREADS, 0, stream>>>(At, Bt, bias, out, O, KT);
    } else {
        wql_fused<<<dim3((M / TILE) * (O / TILE)), THREADS, 0, stream>>>(x, pw, scale, pzp, bias, out, M, O, I, ng);
    }
}